// Round 11
// baseline (1698.777 us; speedup 1.0000x reference)
//
#include <hip/hip_runtime.h>
#include <hip/hip_bf16.h>
#include <cstdint>
#include <cstddef>

#define B_   8
#define S_   2048
#define H_   2048
#define M_   256
#define E_   8
#define HH_  1024
#define BS_  (B_*S_)   // 16384

typedef _Float16 f16;
typedef _Float16 f16x8 __attribute__((ext_vector_type(8)));
typedef _Float16 f16x4 __attribute__((ext_vector_type(4)));
typedef float    f32x4 __attribute__((ext_vector_type(4)));

// gemm2 half-slot: A[256][32k] 16KB + B[256][32k] 16KB = 32KB; ring of 4
#define HSLOT 32768

__device__ __forceinline__ void gl_lds16(const void* g, void* l) {
  __builtin_amdgcn_global_load_lds(
      (const __attribute__((address_space(1))) uint32_t*)g,
      (__attribute__((address_space(3))) uint32_t*)l, 16, 0, 0);
}

// tanh(x) = 1 - 2/(e^{2x}+1); v_exp + v_rcp (no IEEE divide). inf->1, 0->-1.
__device__ __forceinline__ float fast_tanh(float x) {
  float t = __expf(2.f * x);
  float r = __builtin_amdgcn_rcpf(t + 1.f);
  return __builtin_fmaf(-2.f, r, 1.f);
}

// --------------------------------------------------------------------------
// gemm2 kloop: r4/r8 8-phase structure (best measured), ring-4, counted vmcnt.
// --------------------------------------------------------------------------
template<int NG, bool SEG, int KB, class F>
__device__ __forceinline__ void kloop(const char* aBlk, const char* bBlk,
                                      char* ldsc, f32x4 (&acc)[8][4], F&& fold) {
  constexpr int NH = NG * 2;
  const int tid = threadIdx.x, ln = tid & 63, wv = tid >> 6;
  const int l15 = ln & 15, kq = ln >> 4;
  const int wm = wv >> 2, wn = wv & 3;

  const char* aPc[2]; const char* bPc[2];
#pragma unroll
  for (int j = 0; j < 2; ++j) {
    int row = (tid >> 2) + j * 128;
    int kqs = (tid & 3) ^ ((row >> 1) & 3);
    aPc[j] = aBlk + (size_t)row * KB + kqs * 16;
    bPc[j] = bBlk + (size_t)row * KB + kqs * 16;
  }
  const int rowA = wm * 128 + l15;
  const int rowB = wn * 64 + l15;
  const int aRd = rowA * 64 + ((kq ^ ((rowA >> 1) & 3)) << 4);
  const int bRd = 16384 + rowB * 64 + ((kq ^ ((rowB >> 1) & 3)) << 4);
  const int dst0 = tid * 16;

  auto stage2 = [&](int Ht, int op) {
    if (Ht >= NH) return;
    char* sb = ldsc + (Ht & 3) * HSLOT;
    size_t oa, ob;
    if constexpr (SEG) {
      size_t kb = (size_t)((Ht & 31) * 64);
      oa = ((size_t)(Ht >> 5) << 25) + kb;    // he expert stride 32MB
      ob = ((size_t)(Ht >> 5) << 22) + kb;    // W2t expert stride 4MB
    } else { oa = ob = (size_t)Ht * 64; }
    if (op == 0) {
      gl_lds16(aPc[0] + oa, sb + dst0);
      gl_lds16(aPc[1] + oa, sb + 8192 + dst0);
    } else {
      gl_lds16(bPc[0] + ob, sb + 16384 + dst0);
      gl_lds16(bPc[1] + ob, sb + 24576 + dst0);
    }
  };

#pragma unroll
  for (int Ht = 0; Ht < 3; ++Ht) { stage2(Ht, 0); stage2(Ht, 1); }
  asm volatile("s_waitcnt vmcnt(8)" ::: "memory");
  __builtin_amdgcn_s_barrier();

#pragma unroll 1
  for (int g = 0; g < NG; ++g) {
#pragma unroll
    for (int kh = 0; kh < 2; ++kh) {
      const int H = g * 2 + kh;
      const char* sb = ldsc + (H & 3) * HSLOT;
      f16x8 bf[4];
#pragma unroll
      for (int mh = 0; mh < 2; ++mh) {
        f16x8 af[4];
        const char* ab = sb + aRd + mh * 4096;
#pragma unroll
        for (int m = 0; m < 4; ++m) af[m] = *(const f16x8*)(ab + m * 1024);
        if (mh == 0) {
          const char* bb = sb + bRd;
#pragma unroll
          for (int n = 0; n < 4; ++n) bf[n] = *(const f16x8*)(bb + n * 1024);
        }
        stage2(H + 3, mh);
        __builtin_amdgcn_s_barrier();
        asm volatile("s_waitcnt lgkmcnt(0)" ::: "memory");
        __builtin_amdgcn_sched_barrier(0);
        __builtin_amdgcn_s_setprio(1);
#pragma unroll
        for (int m = 0; m < 4; ++m)
#pragma unroll
          for (int n = 0; n < 4; ++n)
            acc[mh * 4 + m][n] = __builtin_amdgcn_mfma_f32_16x16x32_f16(
                af[m], bf[n], acc[mh * 4 + m][n], 0, 0, 0);
        __builtin_amdgcn_s_setprio(0);
        __builtin_amdgcn_sched_barrier(0);
        if (mh == 1) {
          if (H < NH - 3)       { asm volatile("s_waitcnt vmcnt(8)" ::: "memory"); }
          else if (H == NH - 3) { asm volatile("s_waitcnt vmcnt(4)" ::: "memory"); }
          else if (H == NH - 2) { asm volatile("s_waitcnt vmcnt(0)" ::: "memory"); }
        }
        __builtin_amdgcn_s_barrier();
      }
    }
    if constexpr (SEG) { if ((g & 15) == 15) fold(g >> 4); }
  }
}

// ---------------- GEMM1 v11: B direct from global (L2-hot weights) ---------
// 256x256 tile, 8 waves 2Mx4N, wave 128x64. A in LDS ring-4 x 16KB (64KB);
// B-fragments plain C++ global->VGPR loads one half ahead (bfA/bfB ping-pong,
// 16 VGPR carried). Sync: compiler's exact vmcnt wait for bf (in-order
// retirement) also drains all older A-stages before each region barrier ->
// no manual vmcnt in the loop. LDS port/half: A 64KB rd + 16KB DMA ~960cy
// < 1240cy MFMA (was ~1500 with B in LDS -> the 44% lockstep ceiling).
// grid 2048 = (nt 4) x (mt 64) x (e 8), block 512
#define REGION1(H, bfU, bfL)                                                   \
  {                                                                            \
    const char* sb = ldsc + ((H) & 3) * 16384;                                 \
    f16x8 af0[4], af1[4];                                                      \
    _Pragma("unroll")                                                          \
    for (int m = 0; m < 4; ++m) af0[m] = *(const f16x8*)(sb + aRd + m * 1024); \
    _Pragma("unroll")                                                          \
    for (int m = 0; m < 4; ++m) af1[m] = *(const f16x8*)(sb + aRd + 4096 + m * 1024); \
    int Hn = (H) + 1 < 64 ? (H) + 1 : 63;                                      \
    _Pragma("unroll")                                                          \
    for (int n = 0; n < 4; ++n) bfL[n] = *(const f16x8*)(bP[n] + (size_t)Hn * 64); \
    stageA((H) + 3);                                                           \
    __builtin_amdgcn_s_setprio(1);                                             \
    _Pragma("unroll")                                                          \
    for (int m = 0; m < 4; ++m)                                                \
      _Pragma("unroll")                                                        \
      for (int n = 0; n < 4; ++n)                                              \
        acc[m][n] = __builtin_amdgcn_mfma_f32_16x16x32_f16(af0[m], bfU[n], acc[m][n], 0, 0, 0); \
    _Pragma("unroll")                                                          \
    for (int m = 0; m < 4; ++m)                                                \
      _Pragma("unroll")                                                        \
      for (int n = 0; n < 4; ++n)                                              \
        acc[4 + m][n] = __builtin_amdgcn_mfma_f32_16x16x32_f16(af1[m], bfU[n], acc[4 + m][n], 0, 0, 0); \
    __builtin_amdgcn_s_setprio(0);                                             \
    __builtin_amdgcn_s_barrier();                                              \
  }

__global__ __launch_bounds__(512, 2) void gemm1_v11(
    const f16* __restrict__ xf, const f16* __restrict__ W1t,
    const float* __restrict__ b1, f16* __restrict__ he) {
  __shared__ alignas(16) char ldsc[4 * 16384];   // A-only ring, 64KB
  int id = blockIdx.x;
  int logical = (id & 7) * 256 + (id >> 3);      // XCD-bijective (2048 % 8 == 0)
  int e = logical >> 8, mt = (logical >> 2) & 63, nt = logical & 3;
  int brow = mt * 256, bcol = nt * 256;

  const int tid = threadIdx.x, ln = tid & 63, wv = tid >> 6;
  const int l15 = ln & 15, kq = ln >> 4;
  const int wm = wv >> 2, wn = wv & 3;

  const char* aBlk = (const char*)xf + (size_t)brow * 4096;
  const char* bBase = (const char*)W1t + ((size_t)e << 22) + (size_t)bcol * 4096;

  const char* aPc[2];
#pragma unroll
  for (int j = 0; j < 2; ++j) {
    int row = (tid >> 2) + j * 128;
    int kqs = (tid & 3) ^ ((row >> 1) & 3);
    aPc[j] = aBlk + (size_t)row * 4096 + kqs * 16;
  }
  const int rowA = wm * 128 + l15;
  const int aRd = rowA * 64 + ((kq ^ ((rowA >> 1) & 3)) << 4);
  const int dst0 = tid * 16;

  // B fragment pointers: lane -> W1t row (bcol + wn*64 + n*16 + l15), 16B chunk kq
  const char* bP[4];
#pragma unroll
  for (int n = 0; n < 4; ++n) {
    int row = wn * 64 + n * 16 + l15;
    bP[n] = bBase + (size_t)row * 4096 + kq * 16;
  }

  auto stageA = [&](int Ht) {
    if (Ht >= 64) return;
    char* sb = ldsc + (Ht & 3) * 16384;
    size_t ko = (size_t)Ht * 64;
    gl_lds16(aPc[0] + ko, sb + dst0);
    gl_lds16(aPc[1] + ko, sb + 8192 + dst0);
  };

  f32x4 acc[8][4] = {};

  // prologue: stage A halves 0..2 (6 vm ops), publish A(0), then load B(0)
  stageA(0); stageA(1); stageA(2);
  asm volatile("s_waitcnt vmcnt(4)" ::: "memory");
  __builtin_amdgcn_s_barrier();
  f16x8 bfA[4], bfB[4];
#pragma unroll
  for (int n = 0; n < 4; ++n) bfA[n] = *(const f16x8*)(bP[n]);

#pragma unroll 1
  for (int g = 0; g < 32; ++g) {
    REGION1(2 * g,     bfA, bfB);
    REGION1(2 * g + 1, bfB, bfA);
  }

  const int kq4 = kq * 4;
  f16* C = he + ((size_t)e << 24);               // BS*HH = 2^24 elems
#pragma unroll
  for (int n = 0; n < 4; ++n) {
    int gc = bcol + wn * 64 + n * 16 + l15;
    float bias = b1[e * HH_ + gc];
#pragma unroll
    for (int m = 0; m < 8; ++m) {
      int gr0 = brow + wm * 128 + m * 16 + kq4;
#pragma unroll
      for (int r = 0; r < 4; ++r)
        C[(size_t)(gr0 + r) * HH_ + gc] = (f16)fmaxf(acc[m][n][r] + bias, 0.f);
    }
  }
}

// ------- GEMM2: out = sum_e w_e * tanh(he_e @ W2t_e^T + b2_e)  [r8 + nt] ---
// grid 512 = (nt 8) x (mt 64), block 512; K = 8 experts x 1024 continuous
__global__ __launch_bounds__(512, 2) void gemm2_t8(
    const f16* __restrict__ he, const f16* __restrict__ W2t,
    const float* __restrict__ b2, const float* __restrict__ wbuf,
    float* __restrict__ out) {
  __shared__ alignas(16) char ldsc[4 * HSLOT];
  __shared__ float biasLDS[E_][256];
  __shared__ float wLDS[E_];
  int id = blockIdx.x;
  int logical = (id & 7) * 64 + (id >> 3);       // XCD-bijective (512 % 8 == 0)
  int mt = logical >> 3, nt = logical & 7;
  int brow = mt * 256, bcol = nt * 256;
  int bb = brow >> 11;

  const int tid = threadIdx.x, ln = tid & 63, wv = tid >> 6;
  const int l15 = ln & 15, kq4 = (ln >> 4) * 4;
  const int wm = wv >> 2, wn = wv & 3;

  {
    int i = tid;
#pragma unroll
    for (int rep = 0; rep < 4; ++rep, i += 512)
      biasLDS[i >> 8][i & 255] = b2[(size_t)(i >> 8) * H_ + bcol + (i & 255)];
    if (tid < E_) wLDS[tid] = wbuf[bb * E_ + tid];
  }
  __syncthreads();

  const char* aBlk = (const char*)he + (size_t)brow * 2048;
  const char* bBlk = (const char*)W2t + (size_t)bcol * 2048;

  f32x4 acc[8][4] = {};
  f16x4 tot[8][4] = {};

  auto fold = [&](int e) {
    float we = wLDS[e];
#pragma unroll
    for (int n = 0; n < 4; ++n) {
      float bias = biasLDS[e][wn * 64 + n * 16 + l15];
#pragma unroll
      for (int m = 0; m < 8; ++m) {
#pragma unroll
        for (int r = 0; r < 4; ++r) {
          tot[m][n][r] += (f16)(we * fast_tanh(acc[m][n][r] + bias));
          acc[m][n][r] = 0.f;
        }
      }
    }
  };

  kloop<128, true, 2048>(aBlk, bBlk, ldsc, acc, fold);

#pragma unroll
  for (int n = 0; n < 4; ++n) {
    int gc = bcol + wn * 64 + n * 16 + l15;
#pragma unroll
    for (int m = 0; m < 8; ++m) {
      int gr0 = brow + wm * 128 + m * 16 + kq4;
#pragma unroll
      for (int r = 0; r < 4; ++r)
        __builtin_nontemporal_store((float)tot[m][n][r],
                                    &out[(size_t)(gr0 + r) * H_ + gc]);
    }
  }
}

// ------------------------------------------- x -> fp16 + pooled partials
__global__ void convert_x_pool(const float* __restrict__ x, f16* __restrict__ xf,
                               float* __restrict__ partial) {
  int h  = blockIdx.x * 256 + threadIdx.x;
  int sc = blockIdx.y;
  int b  = blockIdx.z;
  size_t base = ((size_t)b * S_ + sc * 64) * H_ + h;
  float sum = 0.f;
#pragma unroll 4
  for (int i = 0; i < 64; ++i) {
    float v = x[base + (size_t)i * H_];
    sum += v;
    xf[base + (size_t)i * H_] = (f16)v;
  }
  partial[((size_t)b * H_ + h) * 32 + sc] = sum;
}

// ----------------------------- router (f32); reduces partial sums directly
__global__ void router_kernel(const float* __restrict__ partial,
                              const float* __restrict__ Wm1, const float* __restrict__ bm1,
                              const float* __restrict__ Wm2, const float* __restrict__ bm2,
                              const float* __restrict__ Wm3, const float* __restrict__ bm3,
                              const float* __restrict__ eff, float* __restrict__ wout) {
  __shared__ float pl[H_];
  __shared__ float h1[M_];
  __shared__ float h2[M_];
  __shared__ float lg[E_];
  int b = blockIdx.x;
  int t = threadIdx.x;

  for (int i = t; i < H_; i += 256) {
    float s = 0.f;
    const float* p = partial + ((size_t)b * H_ + i) * 32;
#pragma unroll
    for (int c = 0; c < 32; ++c) s += p[c];
    pl[i] = s * (1.0f / S_);
  }
  __syncthreads();

  float s = bm1[t];
  for (int k = 0; k < H_; ++k) s += pl[k] * Wm1[(size_t)k * M_ + t];
  h1[t] = fmaxf(s, 0.f);
  __syncthreads();

  s = bm2[t];
  for (int k = 0; k < M_; ++k) s += h1[k] * Wm2[k * M_ + t];
  h2[t] = fmaxf(s, 0.f);
  __syncthreads();

  if (t < E_) {
    float l = bm3[t];
    for (int k = 0; k < M_; ++k) l += h2[k] * Wm3[k * E_ + t];
    lg[t] = l;
  }
  __syncthreads();

  if (t == 0) {
    float p[E_], q[E_];
    float mx = -1e30f;
    for (int e = 0; e < E_; ++e) mx = fmaxf(mx, lg[e]);
    float den = 0.f;
    for (int e = 0; e < E_; ++e) { p[e] = __expf(lg[e] - mx); den += p[e]; }
    float inv = 1.f / den;
    for (int e = 0; e < E_; ++e) q[e] = p[e] * inv * eff[e];
    mx = -1e30f;
    for (int e = 0; e < E_; ++e) mx = fmaxf(mx, q[e]);
    den = 0.f;
    for (int e = 0; e < E_; ++e) { q[e] = __expf(q[e] - mx); den += q[e]; }
    inv = 1.f / den;
    for (int e = 0; e < E_; ++e) wout[b * E_ + e] = q[e] * inv;
  }
}

// ------------------------------------- weight transpose + f32->f16 convert
__global__ void transpose_cvt(const float* __restrict__ in, f16* __restrict__ out,
                              int R, int C) {
  __shared__ f16 tile[32][33];
  int e  = blockIdx.z;
  int c0 = blockIdx.x * 32, r0 = blockIdx.y * 32;
  int tx = threadIdx.x & 31, ty = threadIdx.x >> 5;
  const float* inp = in + (size_t)e * R * C;
  f16* outp = out + (size_t)e * R * C;
#pragma unroll
  for (int i = 0; i < 4; ++i) {
    int r = r0 + ty + i * 8;
    tile[ty + i * 8][tx] = (f16)inp[(size_t)r * C + c0 + tx];
  }
  __syncthreads();
#pragma unroll
  for (int i = 0; i < 4; ++i) {
    int c = c0 + ty + i * 8;
    outp[(size_t)c * R + r0 + tx] = tile[tx][ty + i * 8];
  }
}

// ---------------------------------------------------------------- launch
extern "C" void kernel_launch(void* const* d_in, const int* in_sizes, int n_in,
                              void* d_out, int out_size, void* d_ws, size_t ws_size,
                              hipStream_t stream) {
  const float* x   = (const float*)d_in[0];
  const float* Wm1 = (const float*)d_in[1];
  const float* bm1 = (const float*)d_in[2];
  const float* Wm2 = (const float*)d_in[3];
  const float* bm2 = (const float*)d_in[4];
  const float* Wm3 = (const float*)d_in[5];
  const float* bm3 = (const float*)d_in[6];
  const float* W1  = (const float*)d_in[7];
  const float* b1  = (const float*)d_in[8];
  const float* W2  = (const float*)d_in[9];
  const float* b2  = (const float*)d_in[10];
  const float* eff = (const float*)d_in[11];
  float* out = (float*)d_out;

  char* ws = (char*)d_ws;
  size_t off = 0;
  auto take = [&](size_t bytes) { void* p = ws + off; off += (bytes + 255) & ~(size_t)255; return p; };

  f16*   xf      = (f16*)  take((size_t)BS_ * H_ * 2);        // 64 MB
  f16*   W1t     = (f16*)  take((size_t)E_ * HH_ * H_ * 2);   // 32 MB
  f16*   W2t     = (f16*)  take((size_t)E_ * H_ * HH_ * 2);   // 32 MB
  float* partial = (float*)take((size_t)B_ * H_ * 32 * 4);    // 2 MB
  float* wbuf    = (float*)take(1024);
  f16*   he      = (f16*)  take((size_t)E_ * BS_ * HH_ * 2);  // 256 MB

  convert_x_pool<<<dim3(H_ / 256, S_ / 64, B_), 256, 0, stream>>>(x, xf, partial);
  router_kernel<<<B_, 256, 0, stream>>>(partial, Wm1, bm1, Wm2, bm2, Wm3, bm3, eff, wbuf);
  transpose_cvt<<<dim3(HH_ / 32, H_ / 32, E_), 256, 0, stream>>>(W1, W1t, H_, HH_);
  transpose_cvt<<<dim3(H_ / 32, HH_ / 32, E_), 256, 0, stream>>>(W2, W2t, HH_, H_);

  gemm1_v11<<<2048, 512, 0, stream>>>(xf, W1t, b1, he);
  gemm2_t8<<<512, 512, 0, stream>>>(he, W2t, b2, wbuf, out);
}

// Round 12
// 1336.471 us; speedup vs baseline: 1.2711x; 1.2711x over previous
//
#include <hip/hip_runtime.h>
#include <hip/hip_bf16.h>
#include <cstdint>
#include <cstddef>

#define B_   8
#define S_   2048
#define H_   2048
#define M_   256
#define E_   8
#define HH_  1024
#define BS_  (B_*S_)   // 16384

typedef _Float16 f16;
typedef _Float16 f16x8 __attribute__((ext_vector_type(8)));
typedef _Float16 f16x4 __attribute__((ext_vector_type(4)));
typedef float    f32x4 __attribute__((ext_vector_type(4)));

// half-slot: A[256][32k] 16KB + B[256][32k] 16KB = 32KB; ring of 4
#define HSLOT 32768

__device__ __forceinline__ void gl_lds16(const void* g, void* l) {
  __builtin_amdgcn_global_load_lds(
      (const __attribute__((address_space(1))) uint32_t*)g,
      (__attribute__((address_space(3))) uint32_t*)l, 16, 0, 0);
}

// tanh(x) = 1 - 2/(e^{2x}+1); v_exp + v_rcp (no IEEE divide). inf->1, 0->-1.
__device__ __forceinline__ float fast_tanh(float x) {
  float t = __expf(2.f * x);
  float r = __builtin_amdgcn_rcpf(t + 1.f);
  return __builtin_fmaf(-2.f, r, 1.f);
}

// --------------------------------------------------------------------------
// 8-phase K-loop (r4/r8 structure — best of 6 measured schedule variants):
// 256x256 tile, BK=64 as 2 halves of 32k, waves 2M x 4N, wave tile 128x64.
// LDS ring-4 x 32KB. Swizzle: phys 16B slot = kq ^ ((row>>1)&3)
// (0 conflicts measured, src-permuted). Per phase: {ds_reads, 2 gl_lds,
// barrier, lgkm0, setprio, 16 MFMA, setprio, [vmcnt(8) once/half], barrier}.
// Confirmed model (r10 counters): per half/CU ~1400cy LDS port serializes
// vs ~1240cy MFMA under lockstep -> ~44% MfmaUtil. All attempts to break
// the serialization at HIP level failed (r5/r6/r7/r9/r11) — needs
// inline-asm wave-role schedules (HK/AITER class).
// --------------------------------------------------------------------------
template<int NG, bool SEG, int KB, class F>
__device__ __forceinline__ void kloop(const char* aBlk, const char* bBlk,
                                      char* ldsc, f32x4 (&acc)[8][4], F&& fold) {
  constexpr int NH = NG * 2;
  const int tid = threadIdx.x, ln = tid & 63, wv = tid >> 6;
  const int l15 = ln & 15, kq = ln >> 4;
  const int wm = wv >> 2, wn = wv & 3;

  const char* aPc[2]; const char* bPc[2];
#pragma unroll
  for (int j = 0; j < 2; ++j) {
    int row = (tid >> 2) + j * 128;
    int kqs = (tid & 3) ^ ((row >> 1) & 3);
    aPc[j] = aBlk + (size_t)row * KB + kqs * 16;
    bPc[j] = bBlk + (size_t)row * KB + kqs * 16;
  }
  const int rowA = wm * 128 + l15;
  const int rowB = wn * 64 + l15;
  const int aRd = rowA * 64 + ((kq ^ ((rowA >> 1) & 3)) << 4);
  const int bRd = 16384 + rowB * 64 + ((kq ^ ((rowB >> 1) & 3)) << 4);
  const int dst0 = tid * 16;

  auto stage2 = [&](int Ht, int op) {
    if (Ht >= NH) return;
    char* sb = ldsc + (Ht & 3) * HSLOT;
    size_t oa, ob;
    if constexpr (SEG) {
      size_t kb = (size_t)((Ht & 31) * 64);
      oa = ((size_t)(Ht >> 5) << 25) + kb;    // he expert stride 32MB
      ob = ((size_t)(Ht >> 5) << 22) + kb;    // W2t expert stride 4MB
    } else { oa = ob = (size_t)Ht * 64; }
    if (op == 0) {
      gl_lds16(aPc[0] + oa, sb + dst0);
      gl_lds16(aPc[1] + oa, sb + 8192 + dst0);
    } else {
      gl_lds16(bPc[0] + ob, sb + 16384 + dst0);
      gl_lds16(bPc[1] + ob, sb + 24576 + dst0);
    }
  };

#pragma unroll
  for (int Ht = 0; Ht < 3; ++Ht) { stage2(Ht, 0); stage2(Ht, 1); }
  asm volatile("s_waitcnt vmcnt(8)" ::: "memory");
  __builtin_amdgcn_s_barrier();

#pragma unroll 1
  for (int g = 0; g < NG; ++g) {
#pragma unroll
    for (int kh = 0; kh < 2; ++kh) {
      const int H = g * 2 + kh;
      const char* sb = ldsc + (H & 3) * HSLOT;
      f16x8 bf[4];
#pragma unroll
      for (int mh = 0; mh < 2; ++mh) {
        f16x8 af[4];
        const char* ab = sb + aRd + mh * 4096;
#pragma unroll
        for (int m = 0; m < 4; ++m) af[m] = *(const f16x8*)(ab + m * 1024);
        if (mh == 0) {
          const char* bb = sb + bRd;
#pragma unroll
          for (int n = 0; n < 4; ++n) bf[n] = *(const f16x8*)(bb + n * 1024);
        }
        stage2(H + 3, mh);
        __builtin_amdgcn_s_barrier();
        asm volatile("s_waitcnt lgkmcnt(0)" ::: "memory");
        __builtin_amdgcn_sched_barrier(0);
        __builtin_amdgcn_s_setprio(1);
#pragma unroll
        for (int m = 0; m < 4; ++m)
#pragma unroll
          for (int n = 0; n < 4; ++n)
            acc[mh * 4 + m][n] = __builtin_amdgcn_mfma_f32_16x16x32_f16(
                af[m], bf[n], acc[mh * 4 + m][n], 0, 0, 0);
        __builtin_amdgcn_s_setprio(0);
        __builtin_amdgcn_sched_barrier(0);
        if (mh == 1) {
          if (H < NH - 3)       { asm volatile("s_waitcnt vmcnt(8)" ::: "memory"); }
          else if (H == NH - 3) { asm volatile("s_waitcnt vmcnt(4)" ::: "memory"); }
          else if (H == NH - 2) { asm volatile("s_waitcnt vmcnt(0)" ::: "memory"); }
        }
        __builtin_amdgcn_s_barrier();
      }
    }
    if constexpr (SEG) { if ((g & 15) == 15) fold(g >> 4); }
  }
}

// ----------------- GEMM1: he[e] = relu(xf @ W1t[e]^T + b1[e]) --------------
// grid 2048 = (nt 4) x (mt 64) x (e 8), block 512  [r8 winner, PLAIN stores:
// nt on 2B/16-lane-scatter he-writes measured -100us (r10)]
__global__ __launch_bounds__(512, 2) void gemm1_t8(
    const f16* __restrict__ xf, const f16* __restrict__ W1t,
    const float* __restrict__ b1, f16* __restrict__ he) {
  __shared__ alignas(16) char ldsc[4 * HSLOT];
  int id = blockIdx.x;
  int logical = (id & 7) * 256 + (id >> 3);      // XCD-bijective (2048 % 8 == 0)
  int e = logical >> 8, mt = (logical >> 2) & 63, nt = logical & 3;
  int brow = mt * 256, bcol = nt * 256;

  const char* aBlk = (const char*)xf + (size_t)brow * 4096;
  const char* bBlk = (const char*)W1t + ((size_t)e << 22) + (size_t)bcol * 4096;

  f32x4 acc[8][4] = {};
  kloop<32, false, 4096>(aBlk, bBlk, ldsc, acc, [](int) {});

  const int tid = threadIdx.x, ln = tid & 63, wv = tid >> 6;
  const int l15 = ln & 15, kq4 = (ln >> 4) * 4;
  const int wm = wv >> 2, wn = wv & 3;
  f16* C = he + ((size_t)e << 24);               // BS*HH = 2^24 elems
#pragma unroll
  for (int n = 0; n < 4; ++n) {
    int gc = bcol + wn * 64 + n * 16 + l15;
    float bias = b1[e * HH_ + gc];
#pragma unroll
    for (int m = 0; m < 8; ++m) {
      int gr0 = brow + wm * 128 + m * 16 + kq4;
#pragma unroll
      for (int r = 0; r < 4; ++r)
        C[(size_t)(gr0 + r) * HH_ + gc] = (f16)fmaxf(acc[m][n][r] + bias, 0.f);
    }
  }
}

// ------- GEMM2: out = sum_e w_e * tanh(he_e @ W2t_e^T + b2_e)  [r8 + nt
// out-stores: f32 nt measured neutral-to-positive (611-650 vs 627)] ---------
// grid 512 = (nt 8) x (mt 64), block 512; K = 8 experts x 1024 continuous
__global__ __launch_bounds__(512, 2) void gemm2_t8(
    const f16* __restrict__ he, const f16* __restrict__ W2t,
    const float* __restrict__ b2, const float* __restrict__ wbuf,
    float* __restrict__ out) {
  __shared__ alignas(16) char ldsc[4 * HSLOT];
  __shared__ float biasLDS[E_][256];
  __shared__ float wLDS[E_];
  int id = blockIdx.x;
  int logical = (id & 7) * 64 + (id >> 3);       // XCD-bijective (512 % 8 == 0)
  int mt = logical >> 3, nt = logical & 7;
  int brow = mt * 256, bcol = nt * 256;
  int bb = brow >> 11;

  const int tid = threadIdx.x, ln = tid & 63, wv = tid >> 6;
  const int l15 = ln & 15, kq4 = (ln >> 4) * 4;
  const int wm = wv >> 2, wn = wv & 3;

  {
    int i = tid;
#pragma unroll
    for (int rep = 0; rep < 4; ++rep, i += 512)
      biasLDS[i >> 8][i & 255] = b2[(size_t)(i >> 8) * H_ + bcol + (i & 255)];
    if (tid < E_) wLDS[tid] = wbuf[bb * E_ + tid];
  }
  __syncthreads();

  const char* aBlk = (const char*)he + (size_t)brow * 2048;
  const char* bBlk = (const char*)W2t + (size_t)bcol * 2048;

  f32x4 acc[8][4] = {};
  f16x4 tot[8][4] = {};

  auto fold = [&](int e) {
    float we = wLDS[e];
#pragma unroll
    for (int n = 0; n < 4; ++n) {
      float bias = biasLDS[e][wn * 64 + n * 16 + l15];
#pragma unroll
      for (int m = 0; m < 8; ++m) {
#pragma unroll
        for (int r = 0; r < 4; ++r) {
          tot[m][n][r] += (f16)(we * fast_tanh(acc[m][n][r] + bias));
          acc[m][n][r] = 0.f;
        }
      }
    }
  };

  kloop<128, true, 2048>(aBlk, bBlk, ldsc, acc, fold);

#pragma unroll
  for (int n = 0; n < 4; ++n) {
    int gc = bcol + wn * 64 + n * 16 + l15;
#pragma unroll
    for (int m = 0; m < 8; ++m) {
      int gr0 = brow + wm * 128 + m * 16 + kq4;
#pragma unroll
      for (int r = 0; r < 4; ++r)
        __builtin_nontemporal_store((float)tot[m][n][r],
                                    &out[(size_t)(gr0 + r) * H_ + gc]);
    }
  }
}

// ------------------------------------------- x -> fp16 + pooled partials
__global__ void convert_x_pool(const float* __restrict__ x, f16* __restrict__ xf,
                               float* __restrict__ partial) {
  int h  = blockIdx.x * 256 + threadIdx.x;
  int sc = blockIdx.y;
  int b  = blockIdx.z;
  size_t base = ((size_t)b * S_ + sc * 64) * H_ + h;
  float sum = 0.f;
#pragma unroll 4
  for (int i = 0; i < 64; ++i) {
    float v = x[base + (size_t)i * H_];
    sum += v;
    xf[base + (size_t)i * H_] = (f16)v;
  }
  partial[((size_t)b * H_ + h) * 32 + sc] = sum;
}

// ----------------------------- router (f32); reduces partial sums directly
__global__ void router_kernel(const float* __restrict__ partial,
                              const float* __restrict__ Wm1, const float* __restrict__ bm1,
                              const float* __restrict__ Wm2, const float* __restrict__ bm2,
                              const float* __restrict__ Wm3, const float* __restrict__ bm3,
                              const float* __restrict__ eff, float* __restrict__ wout) {
  __shared__ float pl[H_];
  __shared__ float h1[M_];
  __shared__ float h2[M_];
  __shared__ float lg[E_];
  int b = blockIdx.x;
  int t = threadIdx.x;

  for (int i = t; i < H_; i += 256) {
    float s = 0.f;
    const float* p = partial + ((size_t)b * H_ + i) * 32;
#pragma unroll
    for (int c = 0; c < 32; ++c) s += p[c];
    pl[i] = s * (1.0f / S_);
  }
  __syncthreads();

  float s = bm1[t];
  for (int k = 0; k < H_; ++k) s += pl[k] * Wm1[(size_t)k * M_ + t];
  h1[t] = fmaxf(s, 0.f);
  __syncthreads();

  s = bm2[t];
  for (int k = 0; k < M_; ++k) s += h1[k] * Wm2[k * M_ + t];
  h2[t] = fmaxf(s, 0.f);
  __syncthreads();

  if (t < E_) {
    float l = bm3[t];
    for (int k = 0; k < M_; ++k) l += h2[k] * Wm3[k * E_ + t];
    lg[t] = l;
  }
  __syncthreads();

  if (t == 0) {
    float p[E_], q[E_];
    float mx = -1e30f;
    for (int e = 0; e < E_; ++e) mx = fmaxf(mx, lg[e]);
    float den = 0.f;
    for (int e = 0; e < E_; ++e) { p[e] = __expf(lg[e] - mx); den += p[e]; }
    float inv = 1.f / den;
    for (int e = 0; e < E_; ++e) q[e] = p[e] * inv * eff[e];
    mx = -1e30f;
    for (int e = 0; e < E_; ++e) mx = fmaxf(mx, q[e]);
    den = 0.f;
    for (int e = 0; e < E_; ++e) { q[e] = __expf(q[e] - mx); den += q[e]; }
    inv = 1.f / den;
    for (int e = 0; e < E_; ++e) wout[b * E_ + e] = q[e] * inv;
  }
}

// ------------------------------------- weight transpose + f32->f16 convert
__global__ void transpose_cvt(const float* __restrict__ in, f16* __restrict__ out,
                              int R, int C) {
  __shared__ f16 tile[32][33];
  int e  = blockIdx.z;
  int c0 = blockIdx.x * 32, r0 = blockIdx.y * 32;
  int tx = threadIdx.x & 31, ty = threadIdx.x >> 5;
  const float* inp = in + (size_t)e * R * C;
  f16* outp = out + (size_t)e * R * C;
#pragma unroll
  for (int i = 0; i < 4; ++i) {
    int r = r0 + ty + i * 8;
    tile[ty + i * 8][tx] = (f16)inp[(size_t)r * C + c0 + tx];
  }
  __syncthreads();
#pragma unroll
  for (int i = 0; i < 4; ++i) {
    int c = c0 + ty + i * 8;
    outp[(size_t)c * R + r0 + tx] = tile[tx][ty + i * 8];
  }
}

// ---------------------------------------------------------------- launch
extern "C" void kernel_launch(void* const* d_in, const int* in_sizes, int n_in,
                              void* d_out, int out_size, void* d_ws, size_t ws_size,
                              hipStream_t stream) {
  const float* x   = (const float*)d_in[0];
  const float* Wm1 = (const float*)d_in[1];
  const float* bm1 = (const float*)d_in[2];
  const float* Wm2 = (const float*)d_in[3];
  const float* bm2 = (const float*)d_in[4];
  const float* Wm3 = (const float*)d_in[5];
  const float* bm3 = (const float*)d_in[6];
  const float* W1  = (const float*)d_in[7];
  const float* b1  = (const float*)d_in[8];
  const float* W2  = (const float*)d_in[9];
  const float* b2  = (const float*)d_in[10];
  const float* eff = (const float*)d_in[11];
  float* out = (float*)d_out;

  char* ws = (char*)d_ws;
  size_t off = 0;
  auto take = [&](size_t bytes) { void* p = ws + off; off += (bytes + 255) & ~(size_t)255; return p; };

  f16*   xf      = (f16*)  take((size_t)BS_ * H_ * 2);        // 64 MB
  f16*   W1t     = (f16*)  take((size_t)E_ * HH_ * H_ * 2);   // 32 MB
  f16*   W2t     = (f16*)  take((size_t)E_ * H_ * HH_ * 2);   // 32 MB
  float* partial = (float*)take((size_t)B_ * H_ * 32 * 4);    // 2 MB
  float* wbuf    = (float*)take(1024);
  f16*   he      = (f16*)  take((size_t)E_ * BS_ * HH_ * 2);  // 256 MB

  convert_x_pool<<<dim3(H_ / 256, S_ / 64, B_), 256, 0, stream>>>(x, xf, partial);
  router_kernel<<<B_, 256, 0, stream>>>(partial, Wm1, bm1, Wm2, bm2, Wm3, bm3, eff, wbuf);
  transpose_cvt<<<dim3(HH_ / 32, H_ / 32, E_), 256, 0, stream>>>(W1, W1t, H_, HH_);
  transpose_cvt<<<dim3(H_ / 32, HH_ / 32, E_), 256, 0, stream>>>(W2, W2t, HH_, H_);

  gemm1_t8<<<2048, 512, 0, stream>>>(xf, W1t, b1, he);
  gemm2_t8<<<512, 512, 0, stream>>>(he, W2t, b2, wbuf, out);
}

// Round 13
// 1318.644 us; speedup vs baseline: 1.2883x; 1.0135x over previous
//
#include <hip/hip_runtime.h>
#include <hip/hip_bf16.h>
#include <cstdint>
#include <cstddef>

#define B_   8
#define S_   2048
#define H_   2048
#define M_   256
#define E_   8
#define HH_  1024
#define BS_  (B_*S_)   // 16384

typedef _Float16 f16;
typedef _Float16 f16x8 __attribute__((ext_vector_type(8)));
typedef _Float16 f16x4 __attribute__((ext_vector_type(4)));
typedef float    f32x4 __attribute__((ext_vector_type(4)));

// half-slot: A[256][32k] 16KB + B[256][32k] 16KB = 32KB; ring of 4
#define HSLOT 32768

__device__ __forceinline__ void gl_lds16(const void* g, void* l) {
  __builtin_amdgcn_global_load_lds(
      (const __attribute__((address_space(1))) uint32_t*)g,
      (__attribute__((address_space(3))) uint32_t*)l, 16, 0, 0);
}

// tanh(x) = 1 - 2/(e^{2x}+1); v_exp + v_rcp (no IEEE divide). inf->1, 0->-1.
__device__ __forceinline__ float fast_tanh(float x) {
  float t = __expf(2.f * x);
  float r = __builtin_amdgcn_rcpf(t + 1.f);
  return __builtin_fmaf(-2.f, r, 1.f);
}

// --------------------------------------------------------------------------
// 8-phase K-loop (r4/r8 structure — best of 6 measured schedule variants):
// 256x256 tile, BK=64 as 2 halves of 32k, waves 2M x 4N, wave tile 128x64.
// LDS ring-4 x 32KB. Swizzle: phys 16B slot = kq ^ ((row>>1)&3)
// (0 conflicts measured, src-permuted). Per phase: {ds_reads, 2 gl_lds,
// barrier, lgkm0, setprio, 16 MFMA, setprio, [vmcnt(8) once/half], barrier}.
// Measured ceiling of this structure: ~44-45% MfmaUtil; breaking it needs
// wave-role staggered schedules not expressible through hipcc (6 attempts:
// r5/r6/r7/r9/r11 all neutral-to-regressive). 2-blocks/CU quadrant is
// register-infeasible at this wave tile (acc alone = 128 VGPR).
// --------------------------------------------------------------------------
template<int NG, bool SEG, int KB, class F>
__device__ __forceinline__ void kloop(const char* aBlk, const char* bBlk,
                                      char* ldsc, f32x4 (&acc)[8][4], F&& fold) {
  constexpr int NH = NG * 2;
  const int tid = threadIdx.x, ln = tid & 63, wv = tid >> 6;
  const int l15 = ln & 15, kq = ln >> 4;
  const int wm = wv >> 2, wn = wv & 3;

  const char* aPc[2]; const char* bPc[2];
#pragma unroll
  for (int j = 0; j < 2; ++j) {
    int row = (tid >> 2) + j * 128;
    int kqs = (tid & 3) ^ ((row >> 1) & 3);
    aPc[j] = aBlk + (size_t)row * KB + kqs * 16;
    bPc[j] = bBlk + (size_t)row * KB + kqs * 16;
  }
  const int rowA = wm * 128 + l15;
  const int rowB = wn * 64 + l15;
  const int aRd = rowA * 64 + ((kq ^ ((rowA >> 1) & 3)) << 4);
  const int bRd = 16384 + rowB * 64 + ((kq ^ ((rowB >> 1) & 3)) << 4);
  const int dst0 = tid * 16;

  auto stage2 = [&](int Ht, int op) {
    if (Ht >= NH) return;
    char* sb = ldsc + (Ht & 3) * HSLOT;
    size_t oa, ob;
    if constexpr (SEG) {
      size_t kb = (size_t)((Ht & 31) * 64);
      oa = ((size_t)(Ht >> 5) << 25) + kb;    // he expert stride 32MB
      ob = ((size_t)(Ht >> 5) << 22) + kb;    // W2t expert stride 4MB
    } else { oa = ob = (size_t)Ht * 64; }
    if (op == 0) {
      gl_lds16(aPc[0] + oa, sb + dst0);
      gl_lds16(aPc[1] + oa, sb + 8192 + dst0);
    } else {
      gl_lds16(bPc[0] + ob, sb + 16384 + dst0);
      gl_lds16(bPc[1] + ob, sb + 24576 + dst0);
    }
  };

#pragma unroll
  for (int Ht = 0; Ht < 3; ++Ht) { stage2(Ht, 0); stage2(Ht, 1); }
  asm volatile("s_waitcnt vmcnt(8)" ::: "memory");
  __builtin_amdgcn_s_barrier();

#pragma unroll 1
  for (int g = 0; g < NG; ++g) {
#pragma unroll
    for (int kh = 0; kh < 2; ++kh) {
      const int H = g * 2 + kh;
      const char* sb = ldsc + (H & 3) * HSLOT;
      f16x8 bf[4];
#pragma unroll
      for (int mh = 0; mh < 2; ++mh) {
        f16x8 af[4];
        const char* ab = sb + aRd + mh * 4096;
#pragma unroll
        for (int m = 0; m < 4; ++m) af[m] = *(const f16x8*)(ab + m * 1024);
        if (mh == 0) {
          const char* bb = sb + bRd;
#pragma unroll
          for (int n = 0; n < 4; ++n) bf[n] = *(const f16x8*)(bb + n * 1024);
        }
        stage2(H + 3, mh);
        __builtin_amdgcn_s_barrier();
        asm volatile("s_waitcnt lgkmcnt(0)" ::: "memory");
        __builtin_amdgcn_sched_barrier(0);
        __builtin_amdgcn_s_setprio(1);
#pragma unroll
        for (int m = 0; m < 4; ++m)
#pragma unroll
          for (int n = 0; n < 4; ++n)
            acc[mh * 4 + m][n] = __builtin_amdgcn_mfma_f32_16x16x32_f16(
                af[m], bf[n], acc[mh * 4 + m][n], 0, 0, 0);
        __builtin_amdgcn_s_setprio(0);
        __builtin_amdgcn_sched_barrier(0);
        if (mh == 1) {
          if (H < NH - 3)       { asm volatile("s_waitcnt vmcnt(8)" ::: "memory"); }
          else if (H == NH - 3) { asm volatile("s_waitcnt vmcnt(4)" ::: "memory"); }
          else if (H == NH - 2) { asm volatile("s_waitcnt vmcnt(0)" ::: "memory"); }
        }
        __builtin_amdgcn_s_barrier();
      }
    }
    if constexpr (SEG) { if ((g & 15) == 15) fold(g >> 4); }
  }
}

// ----------------- GEMM1: he[e] = relu(xf @ W1t[e]^T + b1[e]) --------------
// grid 2048 = (nt 4) x (mt 64) x (e 8), block 512  [PLAIN stores: nt on
// 2B scatter he-writes measured -100us in r10]
__global__ __launch_bounds__(512, 2) void gemm1_t8(
    const f16* __restrict__ xf, const f16* __restrict__ W1t,
    const float* __restrict__ b1, f16* __restrict__ he) {
  __shared__ alignas(16) char ldsc[4 * HSLOT];
  int id = blockIdx.x;
  int logical = (id & 7) * 256 + (id >> 3);      // XCD-bijective (2048 % 8 == 0)
  int e = logical >> 8, mt = (logical >> 2) & 63, nt = logical & 3;
  int brow = mt * 256, bcol = nt * 256;

  const char* aBlk = (const char*)xf + (size_t)brow * 4096;
  const char* bBlk = (const char*)W1t + ((size_t)e << 22) + (size_t)bcol * 4096;

  f32x4 acc[8][4] = {};
  kloop<32, false, 4096>(aBlk, bBlk, ldsc, acc, [](int) {});

  const int tid = threadIdx.x, ln = tid & 63, wv = tid >> 6;
  const int l15 = ln & 15, kq4 = (ln >> 4) * 4;
  const int wm = wv >> 2, wn = wv & 3;
  f16* C = he + ((size_t)e << 24);               // BS*HH = 2^24 elems
#pragma unroll
  for (int n = 0; n < 4; ++n) {
    int gc = bcol + wn * 64 + n * 16 + l15;
    float bias = b1[e * HH_ + gc];
#pragma unroll
    for (int m = 0; m < 8; ++m) {
      int gr0 = brow + wm * 128 + m * 16 + kq4;
#pragma unroll
      for (int r = 0; r < 4; ++r)
        C[(size_t)(gr0 + r) * HH_ + gc] = (f16)fmaxf(acc[m][n][r] + bias, 0.f);
    }
  }
}

// ------- GEMM2: out = sum_e w_e * tanh(he_e @ W2t_e^T + b2_e)  [nt f32
// out-stores measured neutral-to-positive] ----------------------------------
// grid 512 = (nt 8) x (mt 64), block 512; K = 8 experts x 1024 continuous
__global__ __launch_bounds__(512, 2) void gemm2_t8(
    const f16* __restrict__ he, const f16* __restrict__ W2t,
    const float* __restrict__ b2, const float* __restrict__ wbuf,
    float* __restrict__ out) {
  __shared__ alignas(16) char ldsc[4 * HSLOT];
  __shared__ float biasLDS[E_][256];
  __shared__ float wLDS[E_];
  int id = blockIdx.x;
  int logical = (id & 7) * 64 + (id >> 3);       // XCD-bijective (512 % 8 == 0)
  int mt = logical >> 3, nt = logical & 7;
  int brow = mt * 256, bcol = nt * 256;
  int bb = brow >> 11;

  const int tid = threadIdx.x, ln = tid & 63, wv = tid >> 6;
  const int l15 = ln & 15, kq4 = (ln >> 4) * 4;
  const int wm = wv >> 2, wn = wv & 3;

  {
    int i = tid;
#pragma unroll
    for (int rep = 0; rep < 4; ++rep, i += 512)
      biasLDS[i >> 8][i & 255] = b2[(size_t)(i >> 8) * H_ + bcol + (i & 255)];
    if (tid < E_) wLDS[tid] = wbuf[bb * E_ + tid];
  }
  __syncthreads();

  const char* aBlk = (const char*)he + (size_t)brow * 2048;
  const char* bBlk = (const char*)W2t + (size_t)bcol * 2048;

  f32x4 acc[8][4] = {};
  f16x4 tot[8][4] = {};

  auto fold = [&](int e) {
    float we = wLDS[e];
#pragma unroll
    for (int n = 0; n < 4; ++n) {
      float bias = biasLDS[e][wn * 64 + n * 16 + l15];
#pragma unroll
      for (int m = 0; m < 8; ++m) {
#pragma unroll
        for (int r = 0; r < 4; ++r) {
          tot[m][n][r] += (f16)(we * fast_tanh(acc[m][n][r] + bias));
          acc[m][n][r] = 0.f;
        }
      }
    }
  };

  kloop<128, true, 2048>(aBlk, bBlk, ldsc, acc, fold);

#pragma unroll
  for (int n = 0; n < 4; ++n) {
    int gc = bcol + wn * 64 + n * 16 + l15;
#pragma unroll
    for (int m = 0; m < 8; ++m) {
      int gr0 = brow + wm * 128 + m * 16 + kq4;
#pragma unroll
      for (int r = 0; r < 4; ++r)
        __builtin_nontemporal_store((float)tot[m][n][r],
                                    &out[(size_t)(gr0 + r) * H_ + gc]);
    }
  }
}

// ------------- merged prep: x->fp16+pool partials AND both W transposes ----
// Independent work units run concurrently in one dispatch (removes 2 launch
// serializations from the pre-GEMM chain). block 256.
//   blocks [0, 2048):            convert_x_pool
//   blocks [2048, 2048+16384):   W1 transpose  (R=H, C=HH)
//   blocks [18432, 18432+16384): W2 transpose  (R=HH, C=H)
__global__ void prep_kernel(const float* __restrict__ x, f16* __restrict__ xf,
                            float* __restrict__ partial,
                            const float* __restrict__ W1, f16* __restrict__ W1t,
                            const float* __restrict__ W2, f16* __restrict__ W2t) {
  int blk = blockIdx.x;
  if (blk < 2048) {
    // ---- convert + pool partials ----
    int h  = (blk & 7) * 256 + threadIdx.x;
    int sc = (blk >> 3) & 31;
    int b  = blk >> 8;
    size_t base = ((size_t)b * S_ + sc * 64) * H_ + h;
    float sum = 0.f;
#pragma unroll 4
    for (int i = 0; i < 64; ++i) {
      float v = x[base + (size_t)i * H_];
      sum += v;
      xf[base + (size_t)i * H_] = (f16)v;
    }
    partial[((size_t)b * H_ + h) * 32 + sc] = sum;
    return;
  }
  // ---- weight transpose + cvt ----
  const float* in; f16* outp; int R, C, c0, r0, e;
  if (blk < 2048 + 16384) {
    int i2 = blk - 2048;
    R = H_; C = HH_;
    c0 = (i2 & 31) * 32; r0 = ((i2 >> 5) & 63) * 32; e = i2 >> 11;
    in = W1; outp = W1t;
  } else {
    int i3 = blk - 2048 - 16384;
    R = HH_; C = H_;
    c0 = (i3 & 63) * 32; r0 = ((i3 >> 6) & 31) * 32; e = i3 >> 11;
    in = W2; outp = W2t;
  }
  __shared__ f16 tile[32][33];
  int tx = threadIdx.x & 31, ty = threadIdx.x >> 5;
  const float* inp = in + (size_t)e * R * C;
  f16* op = outp + (size_t)e * R * C;
#pragma unroll
  for (int i = 0; i < 4; ++i) {
    int r = r0 + ty + i * 8;
    tile[ty + i * 8][tx] = (f16)inp[(size_t)r * C + c0 + tx];
  }
  __syncthreads();
#pragma unroll
  for (int i = 0; i < 4; ++i) {
    int c = c0 + ty + i * 8;
    op[(size_t)c * R + r0 + tx] = tile[tx][ty + i * 8];
  }
}

// ----------------------------- router (f32); reduces partial sums directly
__global__ void router_kernel(const float* __restrict__ partial,
                              const float* __restrict__ Wm1, const float* __restrict__ bm1,
                              const float* __restrict__ Wm2, const float* __restrict__ bm2,
                              const float* __restrict__ Wm3, const float* __restrict__ bm3,
                              const float* __restrict__ eff, float* __restrict__ wout) {
  __shared__ float pl[H_];
  __shared__ float h1[M_];
  __shared__ float h2[M_];
  __shared__ float lg[E_];
  int b = blockIdx.x;
  int t = threadIdx.x;

  for (int i = t; i < H_; i += 256) {
    float s = 0.f;
    const float* p = partial + ((size_t)b * H_ + i) * 32;
#pragma unroll
    for (int c = 0; c < 32; ++c) s += p[c];
    pl[i] = s * (1.0f / S_);
  }
  __syncthreads();

  float s = bm1[t];
  for (int k = 0; k < H_; ++k) s += pl[k] * Wm1[(size_t)k * M_ + t];
  h1[t] = fmaxf(s, 0.f);
  __syncthreads();

  s = bm2[t];
  for (int k = 0; k < M_; ++k) s += h1[k] * Wm2[k * M_ + t];
  h2[t] = fmaxf(s, 0.f);
  __syncthreads();

  if (t < E_) {
    float l = bm3[t];
    for (int k = 0; k < M_; ++k) l += h2[k] * Wm3[k * E_ + t];
    lg[t] = l;
  }
  __syncthreads();

  if (t == 0) {
    float p[E_], q[E_];
    float mx = -1e30f;
    for (int e = 0; e < E_; ++e) mx = fmaxf(mx, lg[e]);
    float den = 0.f;
    for (int e = 0; e < E_; ++e) { p[e] = __expf(lg[e] - mx); den += p[e]; }
    float inv = 1.f / den;
    for (int e = 0; e < E_; ++e) q[e] = p[e] * inv * eff[e];
    mx = -1e30f;
    for (int e = 0; e < E_; ++e) mx = fmaxf(mx, q[e]);
    den = 0.f;
    for (int e = 0; e < E_; ++e) { q[e] = __expf(q[e] - mx); den += q[e]; }
    inv = 1.f / den;
    for (int e = 0; e < E_; ++e) wout[b * E_ + e] = q[e] * inv;
  }
}

// ---------------------------------------------------------------- launch
extern "C" void kernel_launch(void* const* d_in, const int* in_sizes, int n_in,
                              void* d_out, int out_size, void* d_ws, size_t ws_size,
                              hipStream_t stream) {
  const float* x   = (const float*)d_in[0];
  const float* Wm1 = (const float*)d_in[1];
  const float* bm1 = (const float*)d_in[2];
  const float* Wm2 = (const float*)d_in[3];
  const float* bm2 = (const float*)d_in[4];
  const float* Wm3 = (const float*)d_in[5];
  const float* bm3 = (const float*)d_in[6];
  const float* W1  = (const float*)d_in[7];
  const float* b1  = (const float*)d_in[8];
  const float* W2  = (const float*)d_in[9];
  const float* b2  = (const float*)d_in[10];
  const float* eff = (const float*)d_in[11];
  float* out = (float*)d_out;

  char* ws = (char*)d_ws;
  size_t off = 0;
  auto take = [&](size_t bytes) { void* p = ws + off; off += (bytes + 255) & ~(size_t)255; return p; };

  f16*   xf      = (f16*)  take((size_t)BS_ * H_ * 2);        // 64 MB
  f16*   W1t     = (f16*)  take((size_t)E_ * HH_ * H_ * 2);   // 32 MB
  f16*   W2t     = (f16*)  take((size_t)E_ * H_ * HH_ * 2);   // 32 MB
  float* partial = (float*)take((size_t)B_ * H_ * 32 * 4);    // 2 MB
  float* wbuf    = (float*)take(1024);
  f16*   he      = (f16*)  take((size_t)E_ * BS_ * HH_ * 2);  // 256 MB

  prep_kernel<<<2048 + 16384 + 16384, 256, 0, stream>>>(x, xf, partial, W1, W1t, W2, W2t);
  router_kernel<<<B_, 256, 0, stream>>>(partial, Wm1, bm1, Wm2, bm2, Wm3, bm3, eff, wbuf);

  gemm1_t8<<<2048, 512, 0, stream>>>(xf, W1t, b1, he);
  gemm2_t8<<<512, 512, 0, stream>>>(he, W2t, b2, wbuf, out);
}